// Round 1
// baseline (351.350 us; speedup 1.0000x reference)
//
#include <hip/hip_runtime.h>

// Problem constants (fixed by harness setup_inputs)
#define NQT   300
#define HWT   4096
#define CD    256
#define NHEAD 8
#define HDIM  32

// ---------------------------------------------------------------------------
// Generic projection GEMM: Out[M x 256] = ((X [+ Xpos]) @ W + bias) * scale
// W is [256 x 256] row-major (k-major rows). BM=BN=64, BK=16, 256 threads,
// 4x4 micro-tile per thread. fp32 end to end.
// ---------------------------------------------------------------------------
__global__ __launch_bounds__(256) void proj_gemm(
    const float* __restrict__ X, const float* __restrict__ Xpos,
    const float* __restrict__ W, const float* __restrict__ bias,
    float* __restrict__ Out, int M, float scale)
{
    __shared__ float As[16][68];  // [k][row], pad 68 -> 2-way max on hot paths
    __shared__ float Bs[16][64];  // [k][col]
    const int t  = threadIdx.x;
    const int m0 = blockIdx.x * 64;
    const int n0 = blockIdx.y * 64;
    const int tx = t & 15, ty = t >> 4;
    const int ar = t >> 2, ac4 = t & 3;

    float acc[4][4] = {};

    for (int k0 = 0; k0 < 256; k0 += 16) {
        // load tiles to registers
        float4 av = make_float4(0.f, 0.f, 0.f, 0.f);
        const int gr = m0 + ar;
        if (gr < M) {
            av = *(const float4*)(X + (size_t)gr * 256 + k0 + ac4 * 4);
            if (Xpos) {
                float4 pv = *(const float4*)(Xpos + (size_t)gr * 256 + k0 + ac4 * 4);
                av.x += pv.x; av.y += pv.y; av.z += pv.z; av.w += pv.w;
            }
        }
        float4 bv = *(const float4*)(W + (size_t)(k0 + ty) * 256 + n0 + tx * 4);

        __syncthreads();   // previous compute done before overwrite
        As[ac4 * 4 + 0][ar] = av.x;
        As[ac4 * 4 + 1][ar] = av.y;
        As[ac4 * 4 + 2][ar] = av.z;
        As[ac4 * 4 + 3][ar] = av.w;
        *(float4*)&Bs[ty][tx * 4] = bv;
        __syncthreads();

        #pragma unroll
        for (int k = 0; k < 16; ++k) {
            float4 a4 = *(const float4*)&As[k][ty * 4];
            float4 b4 = *(const float4*)&Bs[k][tx * 4];
            float a[4] = {a4.x, a4.y, a4.z, a4.w};
            float b[4] = {b4.x, b4.y, b4.z, b4.w};
            #pragma unroll
            for (int i = 0; i < 4; ++i)
                #pragma unroll
                for (int j = 0; j < 4; ++j)
                    acc[i][j] = fmaf(a[i], b[j], acc[i][j]);
        }
    }

    float4 bb = *(const float4*)(bias + n0 + tx * 4);
    #pragma unroll
    for (int i = 0; i < 4; ++i) {
        int gr = m0 + ty * 4 + i;
        if (gr < M) {
            float4 o;
            o.x = (acc[i][0] + bb.x) * scale;
            o.y = (acc[i][1] + bb.y) * scale;
            o.z = (acc[i][2] + bb.z) * scale;
            o.w = (acc[i][3] + bb.w) * scale;
            *(float4*)(Out + (size_t)gr * 256 + n0 + tx * 4) = o;
        }
    }
}

// ---------------------------------------------------------------------------
// RPE tables: for axis=0 (x): out[b,q,h,x] = (relu(delta_x @ w1 + b1) @ w2)[h]
// One thread per (b,q,pos); weights read via wave-uniform (scalar) loads.
// Output layout: [b*NQ + q][h][64]  (512 floats per (b,q))
// ---------------------------------------------------------------------------
__global__ __launch_bounds__(256) void rpe_kernel(
    const float* __restrict__ refpts,
    const float* __restrict__ w1x, const float* __restrict__ b1x, const float* __restrict__ w2x,
    const float* __restrict__ w1y, const float* __restrict__ b1y, const float* __restrict__ w2y,
    float* __restrict__ outx, float* __restrict__ outy)
{
    const int axis = blockIdx.y;
    const int item = blockIdx.x * 256 + threadIdx.x;          // 0..38399
    const int bq   = __builtin_amdgcn_readfirstlane(item >> 6); // wave-uniform
    const int pos  = item & 63;

    const float* w1 = axis ? w1y : w1x;
    const float* b1 = axis ? b1y : b1x;
    const float* w2 = axis ? w2y : w2x;

    float4 r = *(const float4*)(refpts + (size_t)bq * 4);
    float ctr  = axis ? r.y : r.x;
    float half = (axis ? r.w : r.z) * 0.5f;
    float lo = (ctr - half) * 1024.f;   // * (64 * 16)
    float hi = (ctr + half) * 1024.f;
    float p  = ((float)pos + 0.5f) * 16.f;
    float d0 = lo - p, d1 = hi - p;

    float a0 = 0.f, a1 = 0.f, a2 = 0.f, a3 = 0.f;
    float a4 = 0.f, a5 = 0.f, a6 = 0.f, a7 = 0.f;

    #pragma unroll 4
    for (int hid = 0; hid < 512; ++hid) {
        float hv = fmaf(d0, w1[hid], fmaf(d1, w1[512 + hid], b1[hid]));
        hv = fmaxf(hv, 0.f);
        float4 wA = *(const float4*)(w2 + (size_t)hid * 8);
        float4 wB = *(const float4*)(w2 + (size_t)hid * 8 + 4);
        a0 = fmaf(hv, wA.x, a0); a1 = fmaf(hv, wA.y, a1);
        a2 = fmaf(hv, wA.z, a2); a3 = fmaf(hv, wA.w, a3);
        a4 = fmaf(hv, wB.x, a4); a5 = fmaf(hv, wB.y, a5);
        a6 = fmaf(hv, wB.z, a6); a7 = fmaf(hv, wB.w, a7);
    }

    float* op = (axis ? outy : outx) + (size_t)bq * 512 + pos;
    op[0]   = a0; op[64]  = a1; op[128] = a2; op[192] = a3;
    op[256] = a4; op[320] = a5; op[384] = a6; op[448] = a7;
}

// ---------------------------------------------------------------------------
// Fused flash attention with RPE + padding mask.
// Grid: (ceil(300/16), B*NH). Block 256 = 4 waves.
// Per block: 16 queries of one (b,h); iterate 4096 keys in 128-key tiles.
// Phase 1: thread (qi=t/16, g=t%16) computes 8 logits (keys g+16u), online
//          softmax with 16-lane shfl reductions, writes P to LDS.
// Phase 3: per-wave key-slice (32 keys), lane owns 4 queries x dims {db,db+16};
//          final cross-wave reduction through LDS.
// ---------------------------------------------------------------------------
#define QT 16
#define TK 128

__global__ __launch_bounds__(256) void attn_kernel(
    const float* __restrict__ Q,    // [B][300][256] (pre-scaled)
    const float* __restrict__ K,    // [B][4096][256]
    const float* __restrict__ V,    // [B][4096][256]
    const float* __restrict__ RPX,  // [B*300][8][64]
    const float* __restrict__ RPY,  // [B*300][8][64]
    const float* __restrict__ mask, // [B][4096]
    float* __restrict__ Xout)       // [B][300][256]
{
    __shared__ float Ks[TK][36];
    __shared__ float VsT[32][132];
    __shared__ float Ps[QT][132];
    __shared__ float Rx[QT][66];
    __shared__ float Ry[QT][66];
    __shared__ float Msk[TK];
    __shared__ float Cf[QT];
    __shared__ float Lv[QT];
    __shared__ float AccR[4][QT * 34];

    const int bh = blockIdx.y;
    const int b  = bh >> 3, h = bh & 7;
    const int q0 = blockIdx.x * QT;
    const int t  = threadIdx.x;
    const int wv = t >> 6, lane = t & 63;

    // phase-1 mapping
    const int qi1 = t >> 4;   // 0..15
    const int g   = t & 15;
    // phase-3 mapping
    const int qb = lane >> 4; // 0..3 -> queries qb*4..qb*4+3
    const int db = lane & 15; // dims db and db+16

    // Q row -> registers (replicated across the 16 lanes sharing qi1)
    const int qrow  = q0 + qi1;
    const int qrowc = qrow < NQT ? qrow : NQT - 1;
    const float* qp = Q + ((size_t)(b * NQT + qrowc)) * 256 + h * HDIM;
    float4 qreg[8];
    #pragma unroll
    for (int c = 0; c < 8; ++c) qreg[c] = *(const float4*)(qp + c * 4);

    // RPE tiles
    for (int i = t; i < QT * 64; i += 256) {
        int qq = i >> 6, x = i & 63;
        int qr = q0 + qq; if (qr >= NQT) qr = NQT - 1;
        size_t base = ((size_t)(b * NQT + qr) * 8 + h) * 64 + x;
        Rx[qq][x] = RPX[base];
        Ry[qq][x] = RPY[base];
    }

    float m_r = -1e30f, l_r = 0.f;
    float accq[4][2] = {};

    for (int k0 = 0; k0 < HWT; k0 += TK) {
        __syncthreads();   // previous phase-3 readers done

        // ---- stage K, V^T, mask ----
        #pragma unroll
        for (int i = 0; i < 4; ++i) {
            int j  = t + 256 * i;       // 0..1023
            int kk = j >> 3, seg = j & 7;
            size_t goff = ((size_t)(b * HWT + k0 + kk)) * 256 + h * HDIM + seg * 4;
            float4 kv = *(const float4*)(K + goff);
            float4 vv = *(const float4*)(V + goff);
            *(float4*)&Ks[kk][seg * 4] = kv;
            VsT[seg * 4 + 0][kk] = vv.x;
            VsT[seg * 4 + 1][kk] = vv.y;
            VsT[seg * 4 + 2][kk] = vv.z;
            VsT[seg * 4 + 3][kk] = vv.w;
        }
        if (t < TK) Msk[t] = mask[(size_t)b * HWT + k0 + t];
        __syncthreads();

        // ---- phase 1: logits + online softmax ----
        float pbuf[8];
        float tmax = -1e30f;
        #pragma unroll
        for (int u = 0; u < 8; ++u) {
            int kk = g + 16 * u;
            float dot = 0.f;
            #pragma unroll
            for (int c = 0; c < 8; ++c) {
                float4 kv = *(const float4*)&Ks[kk][c * 4];
                dot = fmaf(qreg[c].x, kv.x, dot);
                dot = fmaf(qreg[c].y, kv.y, dot);
                dot = fmaf(qreg[c].z, kv.z, dot);
                dot = fmaf(qreg[c].w, kv.w, dot);
            }
            int kg = k0 + kk;
            float s = dot + Rx[qi1][kg & 63] + Ry[qi1][kg >> 6]
                          + Msk[kk] * (-100.f);
            pbuf[u] = s;
            tmax = fmaxf(tmax, s);
        }
        #pragma unroll
        for (int off = 8; off; off >>= 1)
            tmax = fmaxf(tmax, __shfl_xor(tmax, off));
        float m_new = fmaxf(m_r, tmax);
        float c = __expf(m_r - m_new);
        float psum = 0.f;
        #pragma unroll
        for (int u = 0; u < 8; ++u) {
            float pv = __expf(pbuf[u] - m_new);
            Ps[qi1][g + 16 * u] = pv;
            psum += pv;
        }
        #pragma unroll
        for (int off = 8; off; off >>= 1)
            psum += __shfl_xor(psum, off);
        l_r = l_r * c + psum;
        m_r = m_new;
        if (g == 0) Cf[qi1] = c;
        __syncthreads();

        // ---- phase 3: PV accumulate over this wave's 32-key slice ----
        float cf[4];
        #pragma unroll
        for (int i = 0; i < 4; ++i) cf[i] = Cf[qb * 4 + i];
        #pragma unroll
        for (int i = 0; i < 4; ++i) { accq[i][0] *= cf[i]; accq[i][1] *= cf[i]; }

        const int kbase = wv * 32;
        #pragma unroll
        for (int kq = 0; kq < 32; kq += 4) {
            int kk = kbase + kq;
            float4 v0 = *(const float4*)&VsT[db][kk];
            float4 v1 = *(const float4*)&VsT[db + 16][kk];
            #pragma unroll
            for (int i = 0; i < 4; ++i) {
                float4 pp = *(const float4*)&Ps[qb * 4 + i][kk];
                accq[i][0] = fmaf(pp.x, v0.x, accq[i][0]);
                accq[i][0] = fmaf(pp.y, v0.y, accq[i][0]);
                accq[i][0] = fmaf(pp.z, v0.z, accq[i][0]);
                accq[i][0] = fmaf(pp.w, v0.w, accq[i][0]);
                accq[i][1] = fmaf(pp.x, v1.x, accq[i][1]);
                accq[i][1] = fmaf(pp.y, v1.y, accq[i][1]);
                accq[i][1] = fmaf(pp.z, v1.z, accq[i][1]);
                accq[i][1] = fmaf(pp.w, v1.w, accq[i][1]);
            }
        }
    }

    if (g == 0) Lv[qi1] = l_r;
    #pragma unroll
    for (int i = 0; i < 4; ++i) {
        AccR[wv][(qb * 4 + i) * 34 + db]      = accq[i][0];
        AccR[wv][(qb * 4 + i) * 34 + db + 16] = accq[i][1];
    }
    __syncthreads();

    // final cross-wave reduce + 1/l + store: thread -> (query t/16, dims 2*(t%16))
    const int oq = t >> 4, od = (t & 15) * 2;
    float r0 = 0.f, r1 = 0.f;
    #pragma unroll
    for (int w = 0; w < 4; ++w) {
        r0 += AccR[w][oq * 34 + od];
        r1 += AccR[w][oq * 34 + od + 1];
    }
    float inv = 1.f / Lv[oq];
    int qrow2 = q0 + oq;
    if (qrow2 < NQT) {
        float2 o; o.x = r0 * inv; o.y = r1 * inv;
        *(float2*)(Xout + ((size_t)(b * NQT + qrow2)) * 256 + h * HDIM + od) = o;
    }
}

// ---------------------------------------------------------------------------
extern "C" void kernel_launch(void* const* d_in, const int* in_sizes, int n_in,
                              void* d_out, int out_size, void* d_ws, size_t ws_size,
                              hipStream_t stream)
{
    (void)in_sizes; (void)n_in; (void)out_size; (void)ws_size;

    const float* raw_query = (const float*)d_in[0];
    const float* query_pos = (const float*)d_in[1];
    const float* refpts    = (const float*)d_in[2];
    const float* raw_src   = (const float*)d_in[3];
    const float* src_pos   = (const float*)d_in[4];
    const float* mask      = (const float*)d_in[5];
    // d_in[6] = input_spatial_shapes (constant 64x64, hardcoded)
    const float* Wq = (const float*)d_in[7];
    const float* bq = (const float*)d_in[8];
    const float* Wk = (const float*)d_in[9];
    const float* bk = (const float*)d_in[10];
    const float* Wv = (const float*)d_in[11];
    const float* bv = (const float*)d_in[12];
    const float* Wp = (const float*)d_in[13];
    const float* bp = (const float*)d_in[14];
    const float* c1w1 = (const float*)d_in[15];
    const float* c1b1 = (const float*)d_in[16];
    const float* c1w2 = (const float*)d_in[17];
    const float* c2w1 = (const float*)d_in[18];
    const float* c2b1 = (const float*)d_in[19];
    const float* c2w2 = (const float*)d_in[20];

    float* ws = (float*)d_ws;
    float* Qf = ws;                  // 600*256    = 153600
    float* Kf = Qf + 153600;         // 8192*256   = 2097152
    float* Vf = Kf + 2097152;        // 8192*256   = 2097152
    float* RX = Vf + 2097152;        // 600*8*64   = 307200
    float* RY = RX + 307200;         // 307200
    float* Xf = RY + 307200;         // 153600

    dim3 blk(256);
    const float qscale = 0.17677669529663687f;  // 32^-0.5

    proj_gemm<<<dim3(10, 4),  blk, 0, stream>>>(raw_query, query_pos, Wq, bq, Qf, 600,  qscale);
    proj_gemm<<<dim3(128, 4), blk, 0, stream>>>(raw_src,   src_pos,   Wk, bk, Kf, 8192, 1.f);
    proj_gemm<<<dim3(128, 4), blk, 0, stream>>>(raw_src,   nullptr,   Wv, bv, Vf, 8192, 1.f);
    rpe_kernel<<<dim3(150, 2), blk, 0, stream>>>(refpts, c1w1, c1b1, c1w2, c2w1, c2b1, c2w2, RX, RY);
    attn_kernel<<<dim3(19, 16), blk, 0, stream>>>(Qf, Kf, Vf, RX, RY, mask, Xf);
    proj_gemm<<<dim3(10, 4),  blk, 0, stream>>>(Xf, nullptr, Wp, bp, (float*)d_out, 600, 1.f);
}